// Round 5
// baseline (280.011 us; speedup 1.0000x reference)
//
#include <hip/hip_runtime.h>
#include <hip/hip_bf16.h>

// Problem constants
constexpr int BATCH   = 16;
constexpr int IN_NC   = 64;
constexpr int OUT_NC  = 64;
constexpr int KS      = 3;
constexpr int FC      = 512;
constexpr int GROUPS  = 4;
constexpr int CNN_PARA = IN_NC * OUT_NC * KS * KS + OUT_NC; // 36928
constexpr int PER_G   = CNN_PARA / GROUPS;                  // 9232
constexpr int IN_PER_G = FC / GROUPS;                       // 128
constexpr int H = 128, W = 128;
constexpr int HO = 126, WO = 126;
constexpr int PIX = HO * WO;                                // 15876
constexpr int WCOUNT = IN_NC * OUT_NC * KS * KS;            // 36864
constexpr int HW = H * W;                                   // 16384

typedef __attribute__((ext_vector_type(8))) short short8;
typedef __attribute__((ext_vector_type(4))) float f32x4;

static __device__ __forceinline__ short bf16_bits(float f) {
    union { __hip_bfloat16 h; short s; } u;
    u.h = __float2bfloat16(f);
    return u.s;
}

// ---------------------------------------------------------------------------
// MLP layer: one wave per output neuron o, computing ALL 16 samples.
// Weight row read exactly once (1 MB total vs 16 MB before). fc_in staged in
// LDS. 16 butterfly reductions per wave.
// ---------------------------------------------------------------------------
__global__ __launch_bounds__(256) void mlp_layer(
    const float* __restrict__ in,    // [BATCH, FC]
    const float* __restrict__ w,     // [FC, FC]
    const float* __restrict__ bias,  // [FC]
    float* __restrict__ out)         // [BATCH, FC]
{
    __shared__ float hs[BATCH * FC]; // 32 KiB
    int tid = threadIdx.x;
    for (int i = tid; i < BATCH * FC; i += 256) hs[i] = in[i];
    __syncthreads();

    int o = blockIdx.x * 4 + (tid >> 6);   // 128 blocks x 4 waves = 512
    int l = tid & 63;
    const float4* wrow = (const float4*)(w + (size_t)o * FC + l * 8);
    float4 w0 = wrow[0], w1 = wrow[1];

    float acc[BATCH];
#pragma unroll
    for (int b = 0; b < BATCH; ++b) {
        const float4* hp = (const float4*)(hs + b * FC + l * 8);
        float4 h0 = hp[0], h1 = hp[1];
        acc[b] = w0.x * h0.x + w0.y * h0.y + w0.z * h0.z + w0.w * h0.w
               + w1.x * h1.x + w1.y * h1.y + w1.z * h1.z + w1.w * h1.w;
    }
#pragma unroll
    for (int off = 32; off > 0; off >>= 1)
#pragma unroll
        for (int b = 0; b < BATCH; ++b)
            acc[b] += __shfl_down(acc[b], off, 64);
    if (l == 0) {
        float bv = bias[o];
#pragma unroll
        for (int b = 0; b < BATCH; ++b) {
            float v = acc[b] + bv;
            out[b * FC + o] = v > 0.f ? v : 0.f;
        }
    }
}

// ---------------------------------------------------------------------------
// Grouped FC: one WAVE per output column j (36928 waves, 9232 blocks).
// Coalesced float2 w3 reads (8B/lane), h2 in LDS, 16-acc butterfly reduce.
// ---------------------------------------------------------------------------
__global__ __launch_bounds__(256) void grouped_fc(
    const float* __restrict__ h2,  // [BATCH, FC]
    const float* __restrict__ w3,  // [GROUPS, PER_G, IN_PER_G]
    const float* __restrict__ b3,  // [CNN_PARA]
    float* __restrict__ wb)        // [BATCH, CNN_PARA]
{
    __shared__ float hs[BATCH * FC]; // 32 KiB
    int tid = threadIdx.x;
    for (int i = tid; i < BATCH * FC; i += 256) hs[i] = h2[i];
    __syncthreads();

    int j = blockIdx.x * 4 + (tid >> 6);   // 9232*4 = 36928 exact
    int l = tid & 63;
    int g = j / PER_G;
    const float2 wv = *(const float2*)(w3 + (size_t)j * IN_PER_G + l * 2);
    const float* hbase = hs + g * IN_PER_G + l * 2;

    float acc[BATCH];
#pragma unroll
    for (int b = 0; b < BATCH; ++b)
        acc[b] = wv.x * hbase[b * FC] + wv.y * hbase[b * FC + 1];
#pragma unroll
    for (int off = 32; off > 0; off >>= 1)
#pragma unroll
        for (int b = 0; b < BATCH; ++b)
            acc[b] += __shfl_down(acc[b], off, 64);
    if (l == 0) {
        float bv = b3[j];
#pragma unroll
        for (int b = 0; b < BATCH; ++b) {
            float v = acc[b] + bv;
            wb[(size_t)b * CNN_PARA + j] = v > 0.f ? v : 0.f;
        }
    }
}

// ---------------------------------------------------------------------------
// wT[b][kykx][oc][ic] (bf16) = wb[b][(oc*64+ic)*9 + kykx]
// ---------------------------------------------------------------------------
__global__ __launch_bounds__(256) void conv_w_transpose(
    const float* __restrict__ wb, __hip_bfloat16* __restrict__ wT)
{
    int idx = blockIdx.x * blockDim.x + threadIdx.x;
    if (idx >= BATCH * 9 * 4096) return;
    int b    = idx / (9 * 4096);
    int r    = idx % (9 * 4096);
    int kykx = r >> 12;
    int q    = r & 4095;
    int oc   = q >> 6;
    int ic   = q & 63;
    float v = wb[(size_t)b * CNN_PARA + (oc * 64 + ic) * 9 + kykx];
    union { __hip_bfloat16 h; short s; } u; u.s = bf16_bits(v);
    wT[idx] = u.h;
}

// ---------------------------------------------------------------------------
// xT[b][h][w][ic] (bf16) = x[b][ic][h][w].  Block per (b,h); LDS transpose.
// ---------------------------------------------------------------------------
__global__ __launch_bounds__(256) void conv_x_transpose(
    const float* __restrict__ x, __hip_bfloat16* __restrict__ xT)
{
    __shared__ float lds[64][129];
    int blk = blockIdx.x;           // 16*128
    int b = blk >> 7, h = blk & 127;
    int tid = threadIdx.x;

    const float* xrow = x + (size_t)b * IN_NC * HW + (size_t)h * W;
#pragma unroll 8
    for (int it = 0; it < 32; ++it) {
        int ic = it * 2 + (tid >> 7);
        int w  = tid & 127;
        lds[ic][w] = xrow[(size_t)ic * HW + w];
    }
    __syncthreads();

    __hip_bfloat16* dst = xT + ((size_t)(b * 128 + h)) * (128 * 64);
#pragma unroll
    for (int i = 0; i < 4; ++i) {
        int chunk = i * 256 + tid;
        int w = chunk >> 3, oct = chunk & 7;
        short8 v;
#pragma unroll
        for (int j = 0; j < 8; ++j) v[j] = bf16_bits(lds[oct * 8 + j][w]);
        *(short8*)(dst + (size_t)w * 64 + oct * 8) = v;
    }
}

// ---------------------------------------------------------------------------
// Implicit-GEMM conv, mfma_f32_16x16x32_bf16.
// Block: one sample b, one output-row PAIR.  4 waves; wave (wv>>1) picks the
// row, (wv&1) picks the 64-px half.  Each wave: 64 px x all 64 oc.
//   acc[4 mf][4 nf] = 64 VGPR; A loaded per (kykx,ks) = 4 short8 (16 VGPR).
//   Each B-frag feeds 4 MFMAs, each A-frag 4 MFMAs (0.5 load-inst/MFMA).
// Fragment layouts (verified): A/B lane l -> elem[(l>>4)*8+j], row/col l&15;
// C/D: col=l&15, row=(l>>4)*4+reg.
// ---------------------------------------------------------------------------
__global__ __launch_bounds__(256, 4) void conv_mfma(
    const __hip_bfloat16* __restrict__ xT,  // [16][128][128][64] + pad
    const __hip_bfloat16* __restrict__ wT,  // [16][9][64][64]
    const float* __restrict__ wb,           // bias source
    float* __restrict__ out)                // [1024][126][126]
{
    // XCD-bijective swizzle: 1008 blocks = 8 * 126; each XCD owns 2 samples,
    // so its xT working set (2 x 2.1 MB) is L2-resident.
    int wg   = blockIdx.x;
    int sblk = (wg & 7) * 126 + (wg >> 3);
    int b    = sblk / 63;
    int rp   = sblk % 63;

    int tid = threadIdx.x;
    int wv = tid >> 6, l = tid & 63;
    int l15 = l & 15, l4 = l >> 4;
    int row = rp * 2 + (wv >> 1);          // 0..125
    int px0 = (wv & 1) * 64;               // wave's 64-px window

    f32x4 acc[4][4];
#pragma unroll
    for (int mf = 0; mf < 4; ++mf)
#pragma unroll
        for (int nf = 0; nf < 4; ++nf) acc[mf][nf] = (f32x4)0.f;

#pragma unroll
    for (int kykx = 0; kykx < 9; ++kykx) {
        int ky = kykx / 3, kx = kykx % 3;
        const __hip_bfloat16* wtile = wT + (size_t)(b * 9 + kykx) * 4096;
        const __hip_bfloat16* xrow =
            xT + ((size_t)(b * 128 + row + ky) * 128 + kx) * 64;
#pragma unroll
        for (int ks = 0; ks < 2; ++ks) {
            int ic0 = ks * 32 + l4 * 8;
            short8 A[4];
#pragma unroll
            for (int mf = 0; mf < 4; ++mf)
                A[mf] = *(const short8*)(wtile + (mf * 16 + l15) * 64 + ic0);
#pragma unroll
            for (int nf = 0; nf < 4; ++nf) {
                int ox = px0 + nf * 16 + l15;   // 0..127 (>=126 masked at store)
                short8 bf = *(const short8*)(xrow + (size_t)ox * 64 + ic0);
#pragma unroll
                for (int mf = 0; mf < 4; ++mf)
                    acc[mf][nf] = __builtin_amdgcn_mfma_f32_16x16x32_bf16(
                        A[mf], bf, acc[mf][nf], 0, 0, 0);
            }
        }
    }

    // bias + masked store.  oc = mf*16 + l4*4 + r ; ox = px0 + nf*16 + l15
    float bias[4][4];
#pragma unroll
    for (int mf = 0; mf < 4; ++mf)
#pragma unroll
        for (int r = 0; r < 4; ++r)
            bias[mf][r] = wb[(size_t)b * CNN_PARA + WCOUNT + mf * 16 + l4 * 4 + r];

#pragma unroll
    for (int mf = 0; mf < 4; ++mf)
#pragma unroll
        for (int nf = 0; nf < 4; ++nf) {
            int ox = px0 + nf * 16 + l15;
            if (ox >= WO) continue;
#pragma unroll
            for (int r = 0; r < 4; ++r) {
                int oc = mf * 16 + l4 * 4 + r;
                out[((size_t)(b * 64 + oc)) * PIX + row * WO + ox]
                    = acc[mf][nf][r] + bias[mf][r];
            }
        }
}

// ---------------------------------------------------------------------------
// Fallback f32 direct conv (only if ws too small — not expected).
// ---------------------------------------------------------------------------
__global__ __launch_bounds__(256) void conv_direct(
    const float* __restrict__ x, const float* __restrict__ wb,
    float* __restrict__ out)
{
    constexpr int NBLK = (PIX + 255) / 256;
    __shared__ float wsm[IN_NC * 9];
    __shared__ float bias_s;
    int bid  = blockIdx.x;
    int tile = bid % NBLK;
    int boc  = bid / NBLK;
    int b = boc >> 6, oc = boc & 63;
    int tid = threadIdx.x;
    const float* wsrc = wb + (size_t)b * CNN_PARA + oc * (IN_NC * 9);
    if (tid < IN_NC * 9 / 4) ((float4*)wsm)[tid] = ((const float4*)wsrc)[tid];
    if (tid == 0) bias_s = wb[(size_t)b * CNN_PARA + WCOUNT + oc];
    __syncthreads();
    int p = tile * 256 + tid;
    if (p >= PIX) return;
    int oy = p / WO, ox = p - oy * WO;
    const float* xb = x + (size_t)b * IN_NC * HW + oy * W + ox;
    float acc = bias_s;
    for (int ic = 0; ic < IN_NC; ++ic) {
        const float* xr = xb + ic * HW;
        const float* wr = wsm + ic * 9;
#pragma unroll
        for (int ky = 0; ky < 3; ++ky) {
            acc += xr[ky * W + 0] * wr[ky * 3 + 0];
            acc += xr[ky * W + 1] * wr[ky * 3 + 1];
            acc += xr[ky * W + 2] * wr[ky * 3 + 2];
        }
    }
    out[(size_t)boc * PIX + p] = acc;
}

// ---------------------------------------------------------------------------
extern "C" void kernel_launch(void* const* d_in, const int* in_sizes, int n_in,
                              void* d_out, int out_size, void* d_ws, size_t ws_size,
                              hipStream_t stream) {
    const float* x     = (const float*)d_in[0];
    const float* fc_in = (const float*)d_in[1];
    const float* w1    = (const float*)d_in[2];
    const float* b1    = (const float*)d_in[3];
    const float* w2    = (const float*)d_in[4];
    const float* b2    = (const float*)d_in[5];
    const float* w3    = (const float*)d_in[6];
    const float* b3    = (const float*)d_in[7];
    float* out = (float*)d_out;

    const size_t off_h1 = 0;
    const size_t off_h2 = off_h1 + (size_t)BATCH * FC * 4;
    const size_t off_wb = off_h2 + (size_t)BATCH * FC * 4;
    const size_t off_wT = off_wb + (size_t)BATCH * CNN_PARA * 4;
    const size_t off_xT = off_wT + (size_t)BATCH * 9 * 4096 * 2;
    const size_t xT_bytes = (size_t)BATCH * 128 * 128 * 64 * 2 + 16384;
    const size_t need = off_xT + xT_bytes;   // ~35.5 MiB

    float* h1 = (float*)((char*)d_ws + off_h1);
    float* h2 = (float*)((char*)d_ws + off_h2);
    float* wb = (float*)((char*)d_ws + off_wb);

    mlp_layer<<<FC / 4, 256, 0, stream>>>(fc_in, w1, b1, h1);
    mlp_layer<<<FC / 4, 256, 0, stream>>>(h1, w2, b2, h2);
    grouped_fc<<<CNN_PARA / 4, 256, 0, stream>>>(h2, w3, b3, wb);

    if (ws_size >= need) {
        __hip_bfloat16* wT = (__hip_bfloat16*)((char*)d_ws + off_wT);
        __hip_bfloat16* xT = (__hip_bfloat16*)((char*)d_ws + off_xT);
        conv_w_transpose<<<(BATCH * 9 * 4096 + 255) / 256, 256, 0, stream>>>(wb, wT);
        conv_x_transpose<<<BATCH * 128, 256, 0, stream>>>(x, xT);
        conv_mfma<<<BATCH * 63, 256, 0, stream>>>(xT, wT, wb, out);
    } else {
        conv_direct<<<BATCH * OUT_NC * ((PIX + 255) / 256), 256, 0, stream>>>(x, wb, out);
    }
}

// Round 10
// 251.727 us; speedup vs baseline: 1.1124x; 1.1124x over previous
//
#include <hip/hip_runtime.h>
#include <hip/hip_bf16.h>

// Problem constants
constexpr int BATCH   = 16;
constexpr int IN_NC   = 64;
constexpr int OUT_NC  = 64;
constexpr int KS      = 3;
constexpr int FC      = 512;
constexpr int GROUPS  = 4;
constexpr int CNN_PARA = IN_NC * OUT_NC * KS * KS + OUT_NC; // 36928
constexpr int PER_G   = CNN_PARA / GROUPS;                  // 9232
constexpr int IN_PER_G = FC / GROUPS;                       // 128
constexpr int H = 128, W = 128;
constexpr int HO = 126, WO = 126;
constexpr int PIX = HO * WO;                                // 15876
constexpr int WCOUNT = IN_NC * OUT_NC * KS * KS;            // 36864
constexpr int HW = H * W;                                   // 16384

typedef __attribute__((ext_vector_type(8))) short short8;
typedef __attribute__((ext_vector_type(4))) float f32x4;

static __device__ __forceinline__ short bf16_bits(float f) {
    union { __hip_bfloat16 h; short s; } u;
    u.h = __float2bfloat16(f);
    return u.s;
}

// ---------------------------------------------------------------------------
// MLP layer: one wave per output neuron o, all 16 samples. Weights read once.
// ---------------------------------------------------------------------------
__global__ __launch_bounds__(256) void mlp_layer(
    const float* __restrict__ in,    // [BATCH, FC]
    const float* __restrict__ w,     // [FC, FC]
    const float* __restrict__ bias,  // [FC]
    float* __restrict__ out)         // [BATCH, FC]
{
    __shared__ float hs[BATCH * FC]; // 32 KiB
    int tid = threadIdx.x;
    for (int i = tid; i < BATCH * FC; i += 256) hs[i] = in[i];
    __syncthreads();

    int o = blockIdx.x * 4 + (tid >> 6);   // 128 blocks x 4 waves = 512
    int l = tid & 63;
    const float4* wrow = (const float4*)(w + (size_t)o * FC + l * 8);
    float4 w0 = wrow[0], w1 = wrow[1];

    float acc[BATCH];
#pragma unroll
    for (int b = 0; b < BATCH; ++b) {
        const float4* hp = (const float4*)(hs + b * FC + l * 8);
        float4 h0 = hp[0], h1 = hp[1];
        acc[b] = w0.x * h0.x + w0.y * h0.y + w0.z * h0.z + w0.w * h0.w
               + w1.x * h1.x + w1.y * h1.y + w1.z * h1.z + w1.w * h1.w;
    }
#pragma unroll
    for (int off = 32; off > 0; off >>= 1)
#pragma unroll
        for (int b = 0; b < BATCH; ++b)
            acc[b] += __shfl_down(acc[b], off, 64);
    if (l == 0) {
        float bv = bias[o];
#pragma unroll
        for (int b = 0; b < BATCH; ++b) {
            float v = acc[b] + bv;
            out[b * FC + o] = v > 0.f ? v : 0.f;
        }
    }
}

// ---------------------------------------------------------------------------
// Grouped FC: one WAVE per output column j (36928 waves).
// ---------------------------------------------------------------------------
__global__ __launch_bounds__(256) void grouped_fc(
    const float* __restrict__ h2,  // [BATCH, FC]
    const float* __restrict__ w3,  // [GROUPS, PER_G, IN_PER_G]
    const float* __restrict__ b3,  // [CNN_PARA]
    float* __restrict__ wb)        // [BATCH, CNN_PARA]
{
    __shared__ float hs[BATCH * FC]; // 32 KiB
    int tid = threadIdx.x;
    for (int i = tid; i < BATCH * FC; i += 256) hs[i] = h2[i];
    __syncthreads();

    int j = blockIdx.x * 4 + (tid >> 6);   // 9232*4 = 36928 exact
    int l = tid & 63;
    int g = j / PER_G;
    const float2 wv = *(const float2*)(w3 + (size_t)j * IN_PER_G + l * 2);
    const float* hbase = hs + g * IN_PER_G + l * 2;

    float acc[BATCH];
#pragma unroll
    for (int b = 0; b < BATCH; ++b)
        acc[b] = wv.x * hbase[b * FC] + wv.y * hbase[b * FC + 1];
#pragma unroll
    for (int off = 32; off > 0; off >>= 1)
#pragma unroll
        for (int b = 0; b < BATCH; ++b)
            acc[b] += __shfl_down(acc[b], off, 64);
    if (l == 0) {
        float bv = b3[j];
#pragma unroll
        for (int b = 0; b < BATCH; ++b) {
            float v = acc[b] + bv;
            wb[(size_t)b * CNN_PARA + j] = v > 0.f ? v : 0.f;
        }
    }
}

// ---------------------------------------------------------------------------
// wT[b][kykx][oc][ic] (bf16) = wb[b][(oc*64+ic)*9 + kykx]
// LDS-staged: coalesced global reads AND coalesced 16B writes.
// ---------------------------------------------------------------------------
__global__ __launch_bounds__(256) void conv_w_transpose(
    const float* __restrict__ wb, __hip_bfloat16* __restrict__ wT)
{
    __shared__ float wsm[8 * 576];   // 18 KiB
    int blk = blockIdx.x;
    int b = blk >> 3, ocg = blk & 7;
    int tid = threadIdx.x;
    const float* src = wb + (size_t)b * CNN_PARA + ocg * 8 * 576;
    for (int i = tid; i < 8 * 576; i += 256) wsm[i] = src[i];
    __syncthreads();

    for (int c = tid; c < 576; c += 256) {
        int kykx  = c / 64;
        int r     = c & 63;
        int oc_l  = r >> 3;
        int icoct = r & 7;
        short8 v;
#pragma unroll
        for (int j = 0; j < 8; ++j)
            v[j] = bf16_bits(wsm[oc_l * 576 + (icoct * 8 + j) * 9 + kykx]);
        *(short8*)(wT + (size_t)b * 9 * 4096 + kykx * 4096
                   + (ocg * 8 + oc_l) * 64 + icoct * 8) = v;
    }
}

// ---------------------------------------------------------------------------
// xT[b][h][w][ic] (bf16) = x[b][ic][h][w].  Block per (b,h); LDS transpose.
// ---------------------------------------------------------------------------
__global__ __launch_bounds__(256) void conv_x_transpose(
    const float* __restrict__ x, __hip_bfloat16* __restrict__ xT)
{
    __shared__ float lds[64][129];
    int blk = blockIdx.x;           // 16*128
    int b = blk >> 7, h = blk & 127;
    int tid = threadIdx.x;

    const float* xrow = x + (size_t)b * IN_NC * HW + (size_t)h * W;
#pragma unroll 8
    for (int it = 0; it < 32; ++it) {
        int ic = it * 2 + (tid >> 7);
        int w  = tid & 127;
        lds[ic][w] = xrow[(size_t)ic * HW + w];
    }
    __syncthreads();

    __hip_bfloat16* dst = xT + ((size_t)(b * 128 + h)) * (128 * 64);
#pragma unroll
    for (int i = 0; i < 4; ++i) {
        int chunk = i * 256 + tid;
        int w = chunk >> 3, oct = chunk & 7;
        short8 v;
#pragma unroll
        for (int j = 0; j < 8; ++j) v[j] = bf16_bits(lds[oct * 8 + j][w]);
        *(short8*)(dst + (size_t)w * 64 + oct * 8) = v;
    }
}

// ---------------------------------------------------------------------------
// Implicit-GEMM conv with REG-STAGED LDS X (no global_load_lds).
// Block: (b, output-row-pair rp).  Stages input rows 2rp..2rp+3 (132 px each,
// last 4 px spill into the following row; values there feed only store-masked
// output columns) = 66 KB LDS.  Staging: linear coalesced global short8 loads
// -> ds_write_b128 at XOR-swizzled address (byte ^= (p&7)<<4).  Reader uses
// the same XOR -> round-trips to linear data, bank-conflict-free-ish.
// 4 waves: (wv>>1) = output row of the pair, (wv&1) = 64-px half.
// ---------------------------------------------------------------------------
constexpr int SLAB_PX    = 132;
constexpr int SLAB_BYTES = SLAB_PX * 64 * 2;   // 16896 (multiple of 128)
constexpr int XS_BYTES   = 4 * SLAB_BYTES;     // 67584
constexpr int NCHUNK     = XS_BYTES / 16;      // 4224 16B chunks

__global__ __launch_bounds__(256, 2) void conv_mfma(
    const __hip_bfloat16* __restrict__ xT,  // [16][128][128][64] + pad
    const __hip_bfloat16* __restrict__ wT,  // [16][9][64][64]
    const float* __restrict__ wb,           // bias source
    float* __restrict__ out)                // [1024][126][126]
{
    __shared__ __align__(16) char xs[XS_BYTES];

    // XCD-bijective swizzle: 1008 = 8 * 126 exactly.
    int wg   = blockIdx.x;
    int sblk = (wg & 7) * 126 + (wg >> 3);
    int b    = sblk / 63;
    int rp   = sblk % 63;

    int tid = threadIdx.x;
    int wv = tid >> 6, l = tid & 63;
    int l15 = l & 15, l4 = l >> 4;

    // ---- reg-staged LDS fill: chunk c = 16 bytes.  Global read is LINEAR
    // (consecutive lanes -> consecutive 16B); LDS write address is swizzled.
    // D = c*16; r = D/SLAB_BYTES; p = (D%SLAB_BYTES)>>7; c16 = D&127.
    {
        const char* xbase = (const char*)xT;
#pragma unroll
        for (int i = 0; i < (NCHUNK + 255) / 256; ++i) {
            int c = tid + i * 256;
            if (c < NCHUNK) {
                int D   = c * 16;
                int r   = D / SLAB_BYTES;
                int rem = D - r * SLAB_BYTES;
                int p   = rem >> 7;
                int c16 = D & 127;
                short8 v = *(const short8*)(xbase
                    + (size_t)(b * 128 + rp * 2 + r) * 16384 + (size_t)(p * 128 + c16));
                *(short8*)(xs + r * SLAB_BYTES + p * 128 + (c16 ^ ((p & 7) << 4))) = v;
            }
        }
    }
    __syncthreads();

    int row = rp * 2 + (wv >> 1);          // output row, 0..125
    int px0 = (wv & 1) * 64;               // wave's 64-px window
    int lr  = wv >> 1;

    f32x4 acc[4][4];
#pragma unroll
    for (int mf = 0; mf < 4; ++mf)
#pragma unroll
        for (int nf = 0; nf < 4; ++nf) acc[mf][nf] = (f32x4)0.f;

#pragma unroll
    for (int kykx = 0; kykx < 9; ++kykx) {
        int ky = kykx / 3, kx = kykx % 3;
        const __hip_bfloat16* wtile = wT + (size_t)(b * 9 + kykx) * 4096;
        const char* xslab = xs + (lr + ky) * SLAB_BYTES;
        int pxk = kx + px0;
        int sw  = ((kx + l15) & 7) << 4;   // p&7 == (kx+l15)&7 (others mult of 8)
#pragma unroll
        for (int ks = 0; ks < 2; ++ks) {
            int ic0  = ks * 32 + l4 * 8;
            int slot = ((ks * 4 + l4) * 16) ^ sw;
            short8 A[4];
#pragma unroll
            for (int mf = 0; mf < 4; ++mf)
                A[mf] = *(const short8*)(wtile + (mf * 16 + l15) * 64 + ic0);
#pragma unroll
            for (int nf = 0; nf < 4; ++nf) {
                int p = pxk + nf * 16 + l15;   // <= 129 < 132, staged
                short8 bfr = *(const short8*)(xslab + p * 128 + slot);
#pragma unroll
                for (int mf = 0; mf < 4; ++mf)
                    acc[mf][nf] = __builtin_amdgcn_mfma_f32_16x16x32_bf16(
                        A[mf], bfr, acc[mf][nf], 0, 0, 0);
            }
        }
    }

    // bias + masked store.  oc = mf*16 + l4*4 + r ; ox = px0 + nf*16 + l15
    float bias[4][4];
#pragma unroll
    for (int mf = 0; mf < 4; ++mf)
#pragma unroll
        for (int r = 0; r < 4; ++r)
            bias[mf][r] = wb[(size_t)b * CNN_PARA + WCOUNT + mf * 16 + l4 * 4 + r];

#pragma unroll
    for (int mf = 0; mf < 4; ++mf)
#pragma unroll
        for (int nf = 0; nf < 4; ++nf) {
            int ox = px0 + nf * 16 + l15;
            if (ox >= WO) continue;
#pragma unroll
            for (int r = 0; r < 4; ++r) {
                int oc = mf * 16 + l4 * 4 + r;
                out[((size_t)(b * 64 + oc)) * PIX + row * WO + ox]
                    = acc[mf][nf][r] + bias[mf][r];
            }
        }
}

// ---------------------------------------------------------------------------
// Fallback f32 direct conv (only if ws too small — not expected).
// ---------------------------------------------------------------------------
__global__ __launch_bounds__(256) void conv_direct(
    const float* __restrict__ x, const float* __restrict__ wb,
    float* __restrict__ out)
{
    constexpr int NBLK = (PIX + 255) / 256;
    __shared__ float wsm[IN_NC * 9];
    __shared__ float bias_s;
    int bid  = blockIdx.x;
    int tile = bid % NBLK;
    int boc  = bid / NBLK;
    int b = boc >> 6, oc = boc & 63;
    int tid = threadIdx.x;
    const float* wsrc = wb + (size_t)b * CNN_PARA + oc * (IN_NC * 9);
    if (tid < IN_NC * 9 / 4) ((float4*)wsm)[tid] = ((const float4*)wsrc)[tid];
    if (tid == 0) bias_s = wb[(size_t)b * CNN_PARA + WCOUNT + oc];
    __syncthreads();
    int p = tile * 256 + tid;
    if (p >= PIX) return;
    int oy = p / WO, ox = p - oy * WO;
    const float* xb = x + (size_t)b * IN_NC * HW + oy * W + ox;
    float acc = bias_s;
    for (int ic = 0; ic < IN_NC; ++ic) {
        const float* xr = xb + ic * HW;
        const float* wr = wsm + ic * 9;
#pragma unroll
        for (int ky = 0; ky < 3; ++ky) {
            acc += xr[ky * W + 0] * wr[ky * 3 + 0];
            acc += xr[ky * W + 1] * wr[ky * 3 + 1];
            acc += xr[ky * W + 2] * wr[ky * 3 + 2];
        }
    }
    out[(size_t)boc * PIX + p] = acc;
}

// ---------------------------------------------------------------------------
extern "C" void kernel_launch(void* const* d_in, const int* in_sizes, int n_in,
                              void* d_out, int out_size, void* d_ws, size_t ws_size,
                              hipStream_t stream) {
    const float* x     = (const float*)d_in[0];
    const float* fc_in = (const float*)d_in[1];
    const float* w1    = (const float*)d_in[2];
    const float* b1    = (const float*)d_in[3];
    const float* w2    = (const float*)d_in[4];
    const float* b2    = (const float*)d_in[5];
    const float* w3    = (const float*)d_in[6];
    const float* b3    = (const float*)d_in[7];
    float* out = (float*)d_out;

    const size_t off_h1 = 0;
    const size_t off_h2 = off_h1 + (size_t)BATCH * FC * 4;
    const size_t off_wb = off_h2 + (size_t)BATCH * FC * 4;
    const size_t off_wT = off_wb + (size_t)BATCH * CNN_PARA * 4;
    const size_t off_xT = off_wT + (size_t)BATCH * 9 * 4096 * 2;
    const size_t xT_bytes = (size_t)BATCH * 128 * 128 * 64 * 2 + 16384;
    const size_t need = off_xT + xT_bytes;   // ~35.5 MiB

    float* h1 = (float*)((char*)d_ws + off_h1);
    float* h2 = (float*)((char*)d_ws + off_h2);
    float* wb = (float*)((char*)d_ws + off_wb);

    mlp_layer<<<FC / 4, 256, 0, stream>>>(fc_in, w1, b1, h1);
    mlp_layer<<<FC / 4, 256, 0, stream>>>(h1, w2, b2, h2);
    grouped_fc<<<CNN_PARA / 4, 256, 0, stream>>>(h2, w3, b3, wb);

    if (ws_size >= need) {
        __hip_bfloat16* wT = (__hip_bfloat16*)((char*)d_ws + off_wT);
        __hip_bfloat16* xT = (__hip_bfloat16*)((char*)d_ws + off_xT);
        conv_w_transpose<<<BATCH * 8, 256, 0, stream>>>(wb, wT);
        conv_x_transpose<<<BATCH * 128, 256, 0, stream>>>(x, xT);
        conv_mfma<<<BATCH * 63, 256, 0, stream>>>(xT, wT, wb, out);
    } else {
        conv_direct<<<BATCH * OUT_NC * ((PIX + 255) / 256), 256, 0, stream>>>(x, wb, out);
    }
}